// Round 2
// baseline (637.631 us; speedup 1.0000x reference)
//
#include <hip/hip_runtime.h>

#define T_TOK 16384
#define HDIM 2048
#define NEXP 12
#define FDIM 256
#define CAP 1707   // ceil(16384/12 * 1.25)

typedef __attribute__((ext_vector_type(8))) short short8;
typedef __attribute__((ext_vector_type(8))) unsigned short ushort8v;
typedef __attribute__((ext_vector_type(4))) float f32x4;

__device__ __forceinline__ unsigned short f2bf(float f) {
    unsigned int u = __float_as_uint(f);
    u += 0x7fffu + ((u >> 16) & 1u);   // RNE
    return (unsigned short)(u >> 16);
}
__device__ __forceinline__ float bf2f(unsigned short u) {
    return __uint_as_float(((unsigned int)u) << 16);
}

__device__ __forceinline__ void gload_lds16(const void* g, void* l) {
    __builtin_amdgcn_global_load_lds(
        (const __attribute__((address_space(1))) unsigned int*)g,
        (__attribute__((address_space(3))) unsigned int*)l, 16, 0, 0);
}

// sum over each contiguous 16-lane row via DPP row_shr; result valid in lane 15 of row
// (row_shr:N -> dest lane i receives src lane i-N; zeros shift in via bound_ctrl)
__device__ __forceinline__ float rsum16(float v) {
    v += __int_as_float(__builtin_amdgcn_update_dpp(0, __float_as_int(v), 0x118, 0xf, 0xf, true)); // shr 8
    v += __int_as_float(__builtin_amdgcn_update_dpp(0, __float_as_int(v), 0x114, 0xf, 0xf, true)); // shr 4
    v += __int_as_float(__builtin_amdgcn_update_dpp(0, __float_as_int(v), 0x112, 0xf, 0xf, true)); // shr 2
    v += __int_as_float(__builtin_amdgcn_update_dpp(0, __float_as_int(v), 0x111, 0xf, 0xf, true)); // shr 1
    return v;  // lane 15 of each 16-lane row holds the full sum
}

// ---------------- fp32 -> bf16 convert, all three weights in one launch ----------------
__global__ void cvt3(const float4* __restrict__ s0, ushort4* __restrict__ d0,
                     const float4* __restrict__ s1, ushort4* __restrict__ d1,
                     const float4* __restrict__ s2, ushort4* __restrict__ d2, int n4) {
    int i = blockIdx.x * blockDim.x + threadIdx.x;
    int stride = gridDim.x * blockDim.x;
    for (; i < 3 * n4; i += stride) {
        const float4* s; ushort4* d; int j;
        if (i < n4)            { s = s0; d = d0; j = i; }
        else if (i < 2 * n4)   { s = s1; d = d1; j = i - n4; }
        else                   { s = s2; d = d2; j = i - 2 * n4; }
        float4 v = s[j];
        ushort4 o;
        o.x = f2bf(v.x); o.y = f2bf(v.y); o.z = f2bf(v.z); o.w = f2bf(v.w);
        d[j] = o;
    }
}

// ---------------- gating: partial logits (fp32) + xb (bf16) ----------------
// wave handles one K-chunk of 256 for 8 tokens. Software-pipelined in pairs:
// next pair's 8 float4 loads are issued before the current pair's FMAs/reduce.
// lane: eg = l>>4 (expert group: experts eg, eg+4, eg+8), kk = l&15.
// Reduce over kk is 4 DPP row_shr adds (VALU); sum lands in kk==15.
__global__ __launch_bounds__(256) void gating_partial(
    const float* __restrict__ x, const float* __restrict__ gw,
    float* __restrict__ part, ushort4* __restrict__ xb4) {
    const int tid = threadIdx.x;
    const int wid = tid >> 6, l = tid & 63;
    const int c = blockIdx.y * 4 + wid;          // chunk 0..7
    const int eg = l >> 4, kk = l & 15;
    const int kbase = c * 256 + kk * 4;

    float4 g[3][4];
#pragma unroll
    for (int ei = 0; ei < 3; ei++) {
        int e = eg + ei * 4;
#pragma unroll
        for (int s = 0; s < 4; s++)
            g[ei][s] = *(const float4*)(gw + e * HDIM + kbase + s * 64);
    }

    const int t0 = blockIdx.x * 8;

    float4 xv[2][4];
#pragma unroll
    for (int u = 0; u < 2; u++)
#pragma unroll
        for (int s = 0; s < 4; s++)
            xv[u][s] = *(const float4*)(x + (size_t)(t0 + u) * HDIM + kbase + s * 64);

#pragma unroll
    for (int tt = 0; tt < 8; tt += 2) {
        // issue next pair's loads first (depth-1 pipeline)
        float4 xn[2][4];
        if (tt < 6) {
#pragma unroll
            for (int u = 0; u < 2; u++)
#pragma unroll
                for (int s = 0; s < 4; s++)
                    xn[u][s] = *(const float4*)(x + (size_t)(t0 + tt + 2 + u) * HDIM + kbase + s * 64);
        }

        float a[2][3];
#pragma unroll
        for (int u = 0; u < 2; u++)
#pragma unroll
            for (int e = 0; e < 3; e++) a[u][e] = 0.f;
#pragma unroll
        for (int s = 0; s < 4; s++) {
#pragma unroll
            for (int u = 0; u < 2; u++) {
                a[u][0] = fmaf(g[0][s].x, xv[u][s].x, a[u][0]); a[u][0] = fmaf(g[0][s].y, xv[u][s].y, a[u][0]);
                a[u][0] = fmaf(g[0][s].z, xv[u][s].z, a[u][0]); a[u][0] = fmaf(g[0][s].w, xv[u][s].w, a[u][0]);
                a[u][1] = fmaf(g[1][s].x, xv[u][s].x, a[u][1]); a[u][1] = fmaf(g[1][s].y, xv[u][s].y, a[u][1]);
                a[u][1] = fmaf(g[1][s].z, xv[u][s].z, a[u][1]); a[u][1] = fmaf(g[1][s].w, xv[u][s].w, a[u][1]);
                a[u][2] = fmaf(g[2][s].x, xv[u][s].x, a[u][2]); a[u][2] = fmaf(g[2][s].y, xv[u][s].y, a[u][2]);
                a[u][2] = fmaf(g[2][s].z, xv[u][s].z, a[u][2]); a[u][2] = fmaf(g[2][s].w, xv[u][s].w, a[u][2]);
            }
        }

        // fused x -> bf16: full-wave store, lane (eg,kk) emits chunk s==eg
#pragma unroll
        for (int u = 0; u < 2; u++) {
            float4 mine = (eg == 0) ? xv[u][0] : (eg == 1) ? xv[u][1] : (eg == 2) ? xv[u][2] : xv[u][3];
            ushort4 o;
            o.x = f2bf(mine.x); o.y = f2bf(mine.y); o.z = f2bf(mine.z); o.w = f2bf(mine.w);
            xb4[((size_t)(t0 + tt + u) * HDIM + c * 256 + eg * 64 + kk * 4) >> 2] = o;
        }

        // reduce over kk (16 contiguous lanes) via DPP; sum lands in kk==15
#pragma unroll
        for (int u = 0; u < 2; u++) {
            a[u][0] = rsum16(a[u][0]);
            a[u][1] = rsum16(a[u][1]);
            a[u][2] = rsum16(a[u][2]);
        }
        if (kk == 15) {
#pragma unroll
            for (int u = 0; u < 2; u++) {
                float* dst = part + ((size_t)c * T_TOK + t0 + tt + u) * 12 + eg;
                dst[0] = a[u][0]; dst[4] = a[u][1]; dst[8] = a[u][2];
            }
        }

        if (tt < 6) {
#pragma unroll
            for (int u = 0; u < 2; u++)
#pragma unroll
                for (int s = 0; s < 4; s++) xv[u][s] = xn[u][s];
        }
    }
}

// ---------------- top-2 + renormalized weights ----------------
__global__ void gating_top2(const float* __restrict__ part,
                            int* __restrict__ sel, float* __restrict__ rw) {
    int t = blockIdx.x * 256 + threadIdx.x;
    float lg[12];
#pragma unroll
    for (int e = 0; e < 12; e++) lg[e] = 0.f;
    for (int c = 0; c < 8; c++) {
        const float* p = part + ((size_t)c * T_TOK + t) * 12;
#pragma unroll
        for (int e = 0; e < 12; e++) lg[e] += p[e];
    }
    float m1 = -1e30f, m2 = -1e30f; int i1 = 0, i2 = 0;
#pragma unroll
    for (int e = 0; e < 12; e++) {
        float v = lg[e];
        if (v > m1) { m2 = m1; i2 = i1; m1 = v; i1 = e; }
        else if (v > m2) { m2 = v; i2 = e; }
    }
    float r0 = 1.f / (1.f + expf(m2 - m1));
    sel[2 * t] = i1; sel[2 * t + 1] = i2;
    rw[2 * t] = r0;  rw[2 * t + 1] = 1.f - r0;
}

// ---------------- routing: per-chunk expert histogram ----------------
__global__ __launch_bounds__(512) void route_count(const int* __restrict__ sel,
                                                   int* __restrict__ counts) {
    __shared__ int h[NEXP];
    if (threadIdx.x < NEXP) h[threadIdx.x] = 0;
    __syncthreads();
    int f = blockIdx.x * 512 + threadIdx.x;
    int k = f >> 14, t = f & (T_TOK - 1);
    atomicAdd(&h[sel[2 * t + k]], 1);
    __syncthreads();
    if (threadIdx.x < NEXP) counts[threadIdx.x * 64 + blockIdx.x] = h[threadIdx.x];
}

// ---------------- routing: emit slot assignments (slot-major flat order) ----------------
__global__ __launch_bounds__(512) void route_emit(const int* __restrict__ sel,
                                                  const int* __restrict__ counts,
                                                  int* __restrict__ tok,
                                                  int* __restrict__ loc) {
    const int e = blockIdx.y, c = blockIdx.x;
    const int tid = threadIdx.x, lane = tid & 63, w = tid >> 6;
    __shared__ int wsum[8];
    int base = 0;
    for (int i = 0; i < c; i++) base += counts[e * 64 + i];
    int f = c * 512 + tid;
    int k = f >> 14, t = f & (T_TOK - 1);
    bool m = (sel[2 * t + k] == e);
    unsigned long long mask = __ballot(m);
    if (lane == 0) wsum[w] = __popcll(mask);
    __syncthreads();
    int off = 0, tot = 0;
#pragma unroll
    for (int i = 0; i < 8; i++) { int v = wsum[i]; tot += v; if (i < w) off += v; }
    if (m) {
        int pos = base + off + __popcll(mask & ((1ull << lane) - 1ull));
        if (pos < CAP) { tok[e * CAP + pos] = t; loc[2 * t + k] = e * CAP + pos; }
        else loc[2 * t + k] = -1;
    }
    if (c == 63) {  // pad unfilled slots with a valid token index (never combined)
        int total = base + tot;
        for (int p = total + tid; p < CAP; p += 512) tok[e * CAP + p] = 0;
    }
}

// ---------------- up-proj GEMM: G = silu((X@W1^T)*(X@W3^T)), bf16 out ----------------
// operand-swapped MFMA: acc holds C^T so reg i spans 4 consecutive F-cols
__global__ __launch_bounds__(256) void up_gemm(
    const unsigned short* __restrict__ xb,
    const unsigned short* __restrict__ w1b,
    const unsigned short* __restrict__ w3b,
    const int* __restrict__ tok,
    unsigned short* __restrict__ G) {
    __shared__ short As[128 * 32];
    __shared__ short B1s[64 * 32];
    __shared__ short B3s[64 * 32];
    const int e = blockIdx.z;
    const int cb = blockIdx.y * 64;
    const int m0 = blockIdx.x * 128;
    const int tid = threadIdx.x, wid = tid >> 6, l = tid & 63;

    const int ar0 = wid * 32 + (l >> 2);
    const int ar1 = ar0 + 16;
    const int tk0 = tok[e * CAP + min(m0 + ar0, CAP - 1)];
    const int tk1 = tok[e * CAP + min(m0 + ar1, CAP - 1)];
    const unsigned short* ga0 = xb + (size_t)tk0 * HDIM + (l & 3) * 8;
    const unsigned short* ga1 = xb + (size_t)tk1 * HDIM + (l & 3) * 8;
    const int bn = wid * 16 + (l >> 2);
    const unsigned short* gb1 = w1b + ((size_t)(e * FDIM + cb + bn)) * HDIM + (l & 3) * 8;
    const unsigned short* gb3 = w3b + ((size_t)(e * FDIM + cb + bn)) * HDIM + (l & 3) * 8;
    short* lA0 = As + (wid * 32) * 32;
    short* lA1 = As + (wid * 32 + 16) * 32;
    short* lB1 = B1s + (wid * 16) * 32;
    short* lB3 = B3s + (wid * 16) * 32;

    const int wm = wid & 1, wn = wid >> 1;
    const int mo = wm * 64, no = wn * 32;
    const int fr = l & 15, fq = l >> 4;

    const f32x4 zf = {0.f, 0.f, 0.f, 0.f};
    f32x4 acc1[2][4], acc3[2][4];   // [nt][mt], transposed product
#pragma unroll
    for (int nt = 0; nt < 2; nt++)
#pragma unroll
        for (int mt = 0; mt < 4; mt++) { acc1[nt][mt] = zf; acc3[nt][mt] = zf; }

    for (int kt = 0; kt < HDIM / 32; kt++) {
        gload_lds16(ga0 + kt * 32, lA0);
        gload_lds16(ga1 + kt * 32, lA1);
        gload_lds16(gb1 + kt * 32, lB1);
        gload_lds16(gb3 + kt * 32, lB3);
        __syncthreads();
        short8 a[4], b1[2], b3[2];
#pragma unroll
        for (int mt = 0; mt < 4; mt++)
            a[mt] = *(const short8*)&As[(mo + mt * 16 + fr) * 32 + fq * 8];
#pragma unroll
        for (int nt = 0; nt < 2; nt++) {
            b1[nt] = *(const short8*)&B1s[(no + nt * 16 + fr) * 32 + fq * 8];
            b3[nt] = *(const short8*)&B3s[(no + nt * 16 + fr) * 32 + fq * 8];
        }
#pragma unroll
        for (int nt = 0; nt < 2; nt++)
#pragma unroll
            for (int mt = 0; mt < 4; mt++) {
                acc1[nt][mt] = __builtin_amdgcn_mfma_f32_16x16x32_bf16(b1[nt], a[mt], acc1[nt][mt], 0, 0, 0);
                acc3[nt][mt] = __builtin_amdgcn_mfma_f32_16x16x32_bf16(b3[nt], a[mt], acc3[nt][mt], 0, 0, 0);
            }
        __syncthreads();
    }
    // epilogue: thread holds rows r = mo+mt*16+fr (slot), cols cb+no+nt*16+fq*4+i
#pragma unroll
    for (int mt = 0; mt < 4; mt++) {
        int r = m0 + mo + mt * 16 + fr;
        if (r < CAP) {
            size_t base = ((size_t)e * CAP + r) * FDIM + cb + no;
#pragma unroll
            for (int nt = 0; nt < 2; nt++) {
                ushort4 o;
                float p;
                p = acc1[nt][mt][0] * acc3[nt][mt][0]; o.x = f2bf(p / (1.f + __expf(-p)));
                p = acc1[nt][mt][1] * acc3[nt][mt][1]; o.y = f2bf(p / (1.f + __expf(-p)));
                p = acc1[nt][mt][2] * acc3[nt][mt][2]; o.z = f2bf(p / (1.f + __expf(-p)));
                p = acc1[nt][mt][3] * acc3[nt][mt][3]; o.w = f2bf(p / (1.f + __expf(-p)));
                *(ushort4*)&G[base + nt * 16 + fq * 4] = o;
            }
        }
    }
}

// ---------------- down-proj GEMM: D[slot] = G[slot] @ W2^T, bf16, NO atomics ----------------
__global__ __launch_bounds__(256) void down_gemm(
    const unsigned short* __restrict__ G,
    const unsigned short* __restrict__ w2b,
    unsigned short* __restrict__ D) {
    __shared__ short As[128 * 32];
    __shared__ short Bs[128 * 32];
    const int e = blockIdx.z;
    const int n0 = blockIdx.y * 128;
    const int m0 = blockIdx.x * 128;
    const int tid = threadIdx.x, wid = tid >> 6, l = tid & 63;

    const int r0 = wid * 32 + (l >> 2);
    const int r1 = r0 + 16;
    const unsigned short* ga0 = G + ((size_t)e * CAP + min(m0 + r0, CAP - 1)) * FDIM + (l & 3) * 8;
    const unsigned short* ga1 = G + ((size_t)e * CAP + min(m0 + r1, CAP - 1)) * FDIM + (l & 3) * 8;
    const unsigned short* gb0 = w2b + ((size_t)(e * HDIM + n0 + r0)) * FDIM + (l & 3) * 8;
    const unsigned short* gb1 = w2b + ((size_t)(e * HDIM + n0 + r1)) * FDIM + (l & 3) * 8;
    short* lA0 = As + (wid * 32) * 32;
    short* lA1 = As + (wid * 32 + 16) * 32;
    short* lB0 = Bs + (wid * 32) * 32;
    short* lB1 = Bs + (wid * 32 + 16) * 32;

    const int wm = wid & 1, wn = wid >> 1;
    const int mo = wm * 64, no = wn * 64;
    const int fr = l & 15, fq = l >> 4;

    const f32x4 zf = {0.f, 0.f, 0.f, 0.f};
    f32x4 acc[4][4];   // [nt][mt], transposed product
#pragma unroll
    for (int nt = 0; nt < 4; nt++)
#pragma unroll
        for (int mt = 0; mt < 4; mt++) acc[nt][mt] = zf;

    for (int kt = 0; kt < FDIM / 32; kt++) {
        gload_lds16(ga0 + kt * 32, lA0);
        gload_lds16(ga1 + kt * 32, lA1);
        gload_lds16(gb0 + kt * 32, lB0);
        gload_lds16(gb1 + kt * 32, lB1);
        __syncthreads();
        short8 a[4], b[4];
#pragma unroll
        for (int mt = 0; mt < 4; mt++)
            a[mt] = *(const short8*)&As[(mo + mt * 16 + fr) * 32 + fq * 8];
#pragma unroll
        for (int nt = 0; nt < 4; nt++)
            b[nt] = *(const short8*)&Bs[(no + nt * 16 + fr) * 32 + fq * 8];
#pragma unroll
        for (int nt = 0; nt < 4; nt++)
#pragma unroll
            for (int mt = 0; mt < 4; mt++)
                acc[nt][mt] = __builtin_amdgcn_mfma_f32_16x16x32_bf16(b[nt], a[mt], acc[nt][mt], 0, 0, 0);
        __syncthreads();
    }
    // thread holds rows r = mo+mt*16+fr (slot), cols n0+no+nt*16+fq*4+i (H)
#pragma unroll
    for (int mt = 0; mt < 4; mt++) {
        int r = m0 + mo + mt * 16 + fr;
        if (r < CAP) {
            size_t base = ((size_t)e * CAP + r) * HDIM + n0 + no;
#pragma unroll
            for (int nt = 0; nt < 4; nt++) {
                ushort4 o;
                o.x = f2bf(acc[nt][mt][0]);
                o.y = f2bf(acc[nt][mt][1]);
                o.z = f2bf(acc[nt][mt][2]);
                o.w = f2bf(acc[nt][mt][3]);
                *(ushort4*)&D[base + nt * 16 + fq * 4] = o;
            }
        }
    }
}

// ---------------- combine: out[t] = w0*D[loc0] + w1*D[loc1] ----------------
__global__ __launch_bounds__(256) void combine(const unsigned short* __restrict__ D,
                                               const int* __restrict__ loc,
                                               const float* __restrict__ rw,
                                               float* __restrict__ out) {
    const int t = blockIdx.x;
    const int h = threadIdx.x * 8;
    const int l0 = loc[2 * t], l1 = loc[2 * t + 1];
    const float w0 = rw[2 * t], w1 = rw[2 * t + 1];
    float acc[8];
#pragma unroll
    for (int i = 0; i < 8; i++) acc[i] = 0.f;
    if (l0 >= 0) {
        ushort8v v = *(const ushort8v*)&D[(size_t)l0 * HDIM + h];
#pragma unroll
        for (int i = 0; i < 8; i++) acc[i] = w0 * bf2f(v[i]);
    }
    if (l1 >= 0) {
        ushort8v v = *(const ushort8v*)&D[(size_t)l1 * HDIM + h];
#pragma unroll
        for (int i = 0; i < 8; i++) acc[i] += w1 * bf2f(v[i]);
    }
    float4 o0 = make_float4(acc[0], acc[1], acc[2], acc[3]);
    float4 o1 = make_float4(acc[4], acc[5], acc[6], acc[7]);
    *(float4*)&out[(size_t)t * HDIM + h] = o0;
    *(float4*)&out[(size_t)t * HDIM + h + 4] = o1;
}

extern "C" void kernel_launch(void* const* d_in, const int* in_sizes, int n_in,
                              void* d_out, int out_size, void* d_ws, size_t ws_size,
                              hipStream_t stream) {
    const float* x  = (const float*)d_in[0];
    const float* gw = (const float*)d_in[1];
    const float* w1 = (const float*)d_in[2];
    const float* w2 = (const float*)d_in[3];
    const float* w3 = (const float*)d_in[4];
    float* out = (float*)d_out;

    char* ws = (char*)d_ws;
    size_t off = 0;
    int* sel = (int*)(ws + off);                off += (size_t)T_TOK * 2 * 4;   // 128K
    int* loc = (int*)(ws + off);                off += (size_t)T_TOK * 2 * 4;   // 128K
    float* rw = (float*)(ws + off);             off += (size_t)T_TOK * 2 * 4;   // 128K
    int* tok = (int*)(ws + off);                off += 82176;                    // 12*1707*4 padded
    int* counts = (int*)(ws + off);             off += 4096;                     // 12*64*4 padded
    unsigned short* w2b = (unsigned short*)(ws + off); off += (size_t)NEXP * HDIM * FDIM * 2;
    unsigned short* G   = (unsigned short*)(ws + off); off += (size_t)NEXP * CAP * FDIM * 2;
    // aliased region R (98.5 MB): phase 1 = part+w1b+w3b+xb; phase 2 = D (84 MB)
    char* R = ws + off;
    float* part = (float*)R;                                                    // 6,291,456 B
    unsigned short* w1b = (unsigned short*)(R + 6291456);                       // 12,582,912 B
    unsigned short* w3b = (unsigned short*)(R + 6291456 + 12582912);            // 12,582,912 B
    unsigned short* xb  = (unsigned short*)(R + 6291456 + 2 * 12582912);        // 67,108,864 B
    unsigned short* D   = (unsigned short*)R;                                   // 83,902,464 B

    const int nw4 = NEXP * FDIM * HDIM / 4;

    cvt3<<<2048, 256, 0, stream>>>((const float4*)w1, (ushort4*)w1b,
                                   (const float4*)w3, (ushort4*)w3b,
                                   (const float4*)w2, (ushort4*)w2b, nw4);
    gating_partial<<<dim3(T_TOK / 8, 2), 256, 0, stream>>>(x, gw, part, (ushort4*)xb);
    gating_top2<<<T_TOK / 256, 256, 0, stream>>>(part, sel, rw);
    route_count<<<64, 512, 0, stream>>>(sel, counts);
    route_emit<<<dim3(64, NEXP), 512, 0, stream>>>(sel, counts, tok, loc);
    up_gemm<<<dim3(14, 4, NEXP), 256, 0, stream>>>(xb, w1b, w3b, tok, G);
    down_gemm<<<dim3(14, 16, NEXP), 256, 0, stream>>>(G, w2b, D);
    combine<<<T_TOK, 256, 0, stream>>>(D, loc, rw, out);
}

// Round 3
// 467.141 us; speedup vs baseline: 1.3650x; 1.3650x over previous
//
#include <hip/hip_runtime.h>

#define T_TOK 16384
#define HDIM 2048
#define NEXP 12
#define FDIM 256
#define CAP 1707   // ceil(16384/12 * 1.25)

typedef __attribute__((ext_vector_type(8))) short short8;
typedef __attribute__((ext_vector_type(8))) unsigned short ushort8v;
typedef __attribute__((ext_vector_type(4))) float f32x4;

__device__ __forceinline__ unsigned short f2bf(float f) {
    unsigned int u = __float_as_uint(f);
    u += 0x7fffu + ((u >> 16) & 1u);   // RNE
    return (unsigned short)(u >> 16);
}
__device__ __forceinline__ float bf2f(unsigned short u) {
    return __uint_as_float(((unsigned int)u) << 16);
}

__device__ __forceinline__ void gload_lds16(const void* g, void* l) {
    __builtin_amdgcn_global_load_lds(
        (const __attribute__((address_space(1))) unsigned int*)g,
        (__attribute__((address_space(3))) unsigned int*)l, 16, 0, 0);
}

// full 64-lane sum, result valid in lane 63.
// row_shr:N -> dest lane i gets lane i-N (within 16-lane row, 0-fill via bound_ctrl)
// row_bcast15 (0x142): lane15 -> lanes 16-31, lane47 -> lanes 48-63
// row_bcast31 (0x143): lane31 -> lanes 32-63
__device__ __forceinline__ float rsum64(float v) {
    v += __int_as_float(__builtin_amdgcn_update_dpp(0, __float_as_int(v), 0x118, 0xf, 0xf, true)); // shr 8
    v += __int_as_float(__builtin_amdgcn_update_dpp(0, __float_as_int(v), 0x114, 0xf, 0xf, true)); // shr 4
    v += __int_as_float(__builtin_amdgcn_update_dpp(0, __float_as_int(v), 0x112, 0xf, 0xf, true)); // shr 2
    v += __int_as_float(__builtin_amdgcn_update_dpp(0, __float_as_int(v), 0x111, 0xf, 0xf, true)); // shr 1
    v += __int_as_float(__builtin_amdgcn_update_dpp(0, __float_as_int(v), 0x142, 0xf, 0xf, true)); // bcast15
    v += __int_as_float(__builtin_amdgcn_update_dpp(0, __float_as_int(v), 0x143, 0xf, 0xf, true)); // bcast31
    return v;  // lane 63 holds the wave-wide sum
}

// ---------------- fp32 -> bf16 convert, all three weights in one launch ----------------
__global__ void cvt3(const float4* __restrict__ s0, ushort4* __restrict__ d0,
                     const float4* __restrict__ s1, ushort4* __restrict__ d1,
                     const float4* __restrict__ s2, ushort4* __restrict__ d2, int n4) {
    int i = blockIdx.x * blockDim.x + threadIdx.x;
    int stride = gridDim.x * blockDim.x;
    for (; i < 3 * n4; i += stride) {
        const float4* s; ushort4* d; int j;
        if (i < n4)            { s = s0; d = d0; j = i; }
        else if (i < 2 * n4)   { s = s1; d = d1; j = i - n4; }
        else                   { s = s2; d = d2; j = i - 2 * n4; }
        float4 v = s[j];
        ushort4 o;
        o.x = f2bf(v.x); o.y = f2bf(v.y); o.z = f2bf(v.z); o.w = f2bf(v.w);
        d[j] = o;
    }
}

// ---------------- gating: partial logits (fp32) + xb (bf16) ----------------
// wave handles one K-chunk of 256 for 8 tokens. lane l owns k-offset l*4:
// one coalesced dwordx4 per token per lane, all 8 issued upfront (8 in flight).
// Each lane accumulates all 12 experts; full-wave reduce = 6 DPP adds/expert.
__global__ __launch_bounds__(256) void gating_partial(
    const float* __restrict__ x, const float* __restrict__ gw,
    float* __restrict__ part, ushort4* __restrict__ xb4) {
    const int tid = threadIdx.x;
    const int wid = tid >> 6, l = tid & 63;
    const int c = blockIdx.y * 4 + wid;          // chunk 0..7
    const int kbase = c * 256 + l * 4;
    const int t0 = blockIdx.x * 8;

    float4 g[12];
#pragma unroll
    for (int e = 0; e < 12; e++)
        g[e] = *(const float4*)(gw + e * HDIM + kbase);

    float4 xt[8];
#pragma unroll
    for (int u = 0; u < 8; u++)
        xt[u] = *(const float4*)(x + (size_t)(t0 + u) * HDIM + kbase);

#pragma unroll
    for (int u = 0; u < 8; u++) {
        // fused x -> bf16 store: full wave, 512B contiguous
        ushort4 o;
        o.x = f2bf(xt[u].x); o.y = f2bf(xt[u].y);
        o.z = f2bf(xt[u].z); o.w = f2bf(xt[u].w);
        xb4[(size_t)(t0 + u) * (HDIM / 4) + c * 64 + l] = o;

        float a[12];
#pragma unroll
        for (int e = 0; e < 12; e++) {
            a[e] = g[e].x * xt[u].x;
            a[e] = fmaf(g[e].y, xt[u].y, a[e]);
            a[e] = fmaf(g[e].z, xt[u].z, a[e]);
            a[e] = fmaf(g[e].w, xt[u].w, a[e]);
        }
#pragma unroll
        for (int e = 0; e < 12; e++) a[e] = rsum64(a[e]);

        if (l == 63) {
            float* dst = part + ((size_t)c * T_TOK + t0 + u) * 12;
            *(float4*)(dst)     = make_float4(a[0], a[1], a[2], a[3]);
            *(float4*)(dst + 4) = make_float4(a[4], a[5], a[6], a[7]);
            *(float4*)(dst + 8) = make_float4(a[8], a[9], a[10], a[11]);
        }
    }
}

// ---------------- top-2 + renormalized weights ----------------
__global__ void gating_top2(const float* __restrict__ part,
                            int* __restrict__ sel, float* __restrict__ rw) {
    int t = blockIdx.x * 256 + threadIdx.x;
    float lg[12];
#pragma unroll
    for (int e = 0; e < 12; e++) lg[e] = 0.f;
    for (int c = 0; c < 8; c++) {
        const float* p = part + ((size_t)c * T_TOK + t) * 12;
#pragma unroll
        for (int e = 0; e < 12; e++) lg[e] += p[e];
    }
    float m1 = -1e30f, m2 = -1e30f; int i1 = 0, i2 = 0;
#pragma unroll
    for (int e = 0; e < 12; e++) {
        float v = lg[e];
        if (v > m1) { m2 = m1; i2 = i1; m1 = v; i1 = e; }
        else if (v > m2) { m2 = v; i2 = e; }
    }
    float r0 = 1.f / (1.f + expf(m2 - m1));
    sel[2 * t] = i1; sel[2 * t + 1] = i2;
    rw[2 * t] = r0;  rw[2 * t + 1] = 1.f - r0;
}

// ---------------- routing: per-chunk expert histogram ----------------
__global__ __launch_bounds__(512) void route_count(const int* __restrict__ sel,
                                                   int* __restrict__ counts) {
    __shared__ int h[NEXP];
    if (threadIdx.x < NEXP) h[threadIdx.x] = 0;
    __syncthreads();
    int f = blockIdx.x * 512 + threadIdx.x;
    int k = f >> 14, t = f & (T_TOK - 1);
    atomicAdd(&h[sel[2 * t + k]], 1);
    __syncthreads();
    if (threadIdx.x < NEXP) counts[threadIdx.x * 64 + blockIdx.x] = h[threadIdx.x];
}

// ---------------- routing: emit slot assignments (slot-major flat order) ----------------
__global__ __launch_bounds__(512) void route_emit(const int* __restrict__ sel,
                                                  const int* __restrict__ counts,
                                                  int* __restrict__ tok,
                                                  int* __restrict__ loc) {
    const int e = blockIdx.y, c = blockIdx.x;
    const int tid = threadIdx.x, lane = tid & 63, w = tid >> 6;
    __shared__ int wsum[8];
    int base = 0;
    for (int i = 0; i < c; i++) base += counts[e * 64 + i];
    int f = c * 512 + tid;
    int k = f >> 14, t = f & (T_TOK - 1);
    bool m = (sel[2 * t + k] == e);
    unsigned long long mask = __ballot(m);
    if (lane == 0) wsum[w] = __popcll(mask);
    __syncthreads();
    int off = 0, tot = 0;
#pragma unroll
    for (int i = 0; i < 8; i++) { int v = wsum[i]; tot += v; if (i < w) off += v; }
    if (m) {
        int pos = base + off + __popcll(mask & ((1ull << lane) - 1ull));
        if (pos < CAP) { tok[e * CAP + pos] = t; loc[2 * t + k] = e * CAP + pos; }
        else loc[2 * t + k] = -1;
    }
    if (c == 63) {  // pad unfilled slots with a valid token index (never combined)
        int total = base + tot;
        for (int p = total + tid; p < CAP; p += 512) tok[e * CAP + p] = 0;
    }
}

// ---------------- up-proj GEMM: G = silu((X@W1^T)*(X@W3^T)), bf16 out ----------------
// operand-swapped MFMA: acc holds C^T so reg i spans 4 consecutive F-cols
__global__ __launch_bounds__(256) void up_gemm(
    const unsigned short* __restrict__ xb,
    const unsigned short* __restrict__ w1b,
    const unsigned short* __restrict__ w3b,
    const int* __restrict__ tok,
    unsigned short* __restrict__ G) {
    __shared__ short As[128 * 32];
    __shared__ short B1s[64 * 32];
    __shared__ short B3s[64 * 32];
    const int e = blockIdx.z;
    const int cb = blockIdx.y * 64;
    const int m0 = blockIdx.x * 128;
    const int tid = threadIdx.x, wid = tid >> 6, l = tid & 63;

    const int ar0 = wid * 32 + (l >> 2);
    const int ar1 = ar0 + 16;
    const int tk0 = tok[e * CAP + min(m0 + ar0, CAP - 1)];
    const int tk1 = tok[e * CAP + min(m0 + ar1, CAP - 1)];
    const unsigned short* ga0 = xb + (size_t)tk0 * HDIM + (l & 3) * 8;
    const unsigned short* ga1 = xb + (size_t)tk1 * HDIM + (l & 3) * 8;
    const int bn = wid * 16 + (l >> 2);
    const unsigned short* gb1 = w1b + ((size_t)(e * FDIM + cb + bn)) * HDIM + (l & 3) * 8;
    const unsigned short* gb3 = w3b + ((size_t)(e * FDIM + cb + bn)) * HDIM + (l & 3) * 8;
    short* lA0 = As + (wid * 32) * 32;
    short* lA1 = As + (wid * 32 + 16) * 32;
    short* lB1 = B1s + (wid * 16) * 32;
    short* lB3 = B3s + (wid * 16) * 32;

    const int wm = wid & 1, wn = wid >> 1;
    const int mo = wm * 64, no = wn * 32;
    const int fr = l & 15, fq = l >> 4;

    const f32x4 zf = {0.f, 0.f, 0.f, 0.f};
    f32x4 acc1[2][4], acc3[2][4];   // [nt][mt], transposed product
#pragma unroll
    for (int nt = 0; nt < 2; nt++)
#pragma unroll
        for (int mt = 0; mt < 4; mt++) { acc1[nt][mt] = zf; acc3[nt][mt] = zf; }

    for (int kt = 0; kt < HDIM / 32; kt++) {
        gload_lds16(ga0 + kt * 32, lA0);
        gload_lds16(ga1 + kt * 32, lA1);
        gload_lds16(gb1 + kt * 32, lB1);
        gload_lds16(gb3 + kt * 32, lB3);
        __syncthreads();
        short8 a[4], b1[2], b3[2];
#pragma unroll
        for (int mt = 0; mt < 4; mt++)
            a[mt] = *(const short8*)&As[(mo + mt * 16 + fr) * 32 + fq * 8];
#pragma unroll
        for (int nt = 0; nt < 2; nt++) {
            b1[nt] = *(const short8*)&B1s[(no + nt * 16 + fr) * 32 + fq * 8];
            b3[nt] = *(const short8*)&B3s[(no + nt * 16 + fr) * 32 + fq * 8];
        }
#pragma unroll
        for (int nt = 0; nt < 2; nt++)
#pragma unroll
            for (int mt = 0; mt < 4; mt++) {
                acc1[nt][mt] = __builtin_amdgcn_mfma_f32_16x16x32_bf16(b1[nt], a[mt], acc1[nt][mt], 0, 0, 0);
                acc3[nt][mt] = __builtin_amdgcn_mfma_f32_16x16x32_bf16(b3[nt], a[mt], acc3[nt][mt], 0, 0, 0);
            }
        __syncthreads();
    }
    // epilogue: thread holds rows r = mo+mt*16+fr (slot), cols cb+no+nt*16+fq*4+i
#pragma unroll
    for (int mt = 0; mt < 4; mt++) {
        int r = m0 + mo + mt * 16 + fr;
        if (r < CAP) {
            size_t base = ((size_t)e * CAP + r) * FDIM + cb + no;
#pragma unroll
            for (int nt = 0; nt < 2; nt++) {
                ushort4 o;
                float p;
                p = acc1[nt][mt][0] * acc3[nt][mt][0]; o.x = f2bf(p / (1.f + __expf(-p)));
                p = acc1[nt][mt][1] * acc3[nt][mt][1]; o.y = f2bf(p / (1.f + __expf(-p)));
                p = acc1[nt][mt][2] * acc3[nt][mt][2]; o.z = f2bf(p / (1.f + __expf(-p)));
                p = acc1[nt][mt][3] * acc3[nt][mt][3]; o.w = f2bf(p / (1.f + __expf(-p)));
                *(ushort4*)&G[base + nt * 16 + fq * 4] = o;
            }
        }
    }
}

// ---------------- down-proj GEMM: D[slot] = G[slot] @ W2^T, bf16, NO atomics ----------------
__global__ __launch_bounds__(256) void down_gemm(
    const unsigned short* __restrict__ G,
    const unsigned short* __restrict__ w2b,
    unsigned short* __restrict__ D) {
    __shared__ short As[128 * 32];
    __shared__ short Bs[128 * 32];
    const int e = blockIdx.z;
    const int n0 = blockIdx.y * 128;
    const int m0 = blockIdx.x * 128;
    const int tid = threadIdx.x, wid = tid >> 6, l = tid & 63;

    const int r0 = wid * 32 + (l >> 2);
    const int r1 = r0 + 16;
    const unsigned short* ga0 = G + ((size_t)e * CAP + min(m0 + r0, CAP - 1)) * FDIM + (l & 3) * 8;
    const unsigned short* ga1 = G + ((size_t)e * CAP + min(m0 + r1, CAP - 1)) * FDIM + (l & 3) * 8;
    const unsigned short* gb0 = w2b + ((size_t)(e * HDIM + n0 + r0)) * FDIM + (l & 3) * 8;
    const unsigned short* gb1 = w2b + ((size_t)(e * HDIM + n0 + r1)) * FDIM + (l & 3) * 8;
    short* lA0 = As + (wid * 32) * 32;
    short* lA1 = As + (wid * 32 + 16) * 32;
    short* lB0 = Bs + (wid * 32) * 32;
    short* lB1 = Bs + (wid * 32 + 16) * 32;

    const int wm = wid & 1, wn = wid >> 1;
    const int mo = wm * 64, no = wn * 64;
    const int fr = l & 15, fq = l >> 4;

    const f32x4 zf = {0.f, 0.f, 0.f, 0.f};
    f32x4 acc[4][4];   // [nt][mt], transposed product
#pragma unroll
    for (int nt = 0; nt < 4; nt++)
#pragma unroll
        for (int mt = 0; mt < 4; mt++) acc[nt][mt] = zf;

    for (int kt = 0; kt < FDIM / 32; kt++) {
        gload_lds16(ga0 + kt * 32, lA0);
        gload_lds16(ga1 + kt * 32, lA1);
        gload_lds16(gb0 + kt * 32, lB0);
        gload_lds16(gb1 + kt * 32, lB1);
        __syncthreads();
        short8 a[4], b[4];
#pragma unroll
        for (int mt = 0; mt < 4; mt++)
            a[mt] = *(const short8*)&As[(mo + mt * 16 + fr) * 32 + fq * 8];
#pragma unroll
        for (int nt = 0; nt < 4; nt++)
            b[nt] = *(const short8*)&Bs[(no + nt * 16 + fr) * 32 + fq * 8];
#pragma unroll
        for (int nt = 0; nt < 4; nt++)
#pragma unroll
            for (int mt = 0; mt < 4; mt++)
                acc[nt][mt] = __builtin_amdgcn_mfma_f32_16x16x32_bf16(b[nt], a[mt], acc[nt][mt], 0, 0, 0);
        __syncthreads();
    }
    // thread holds rows r = mo+mt*16+fr (slot), cols n0+no+nt*16+fq*4+i (H)
#pragma unroll
    for (int mt = 0; mt < 4; mt++) {
        int r = m0 + mo + mt * 16 + fr;
        if (r < CAP) {
            size_t base = ((size_t)e * CAP + r) * HDIM + n0 + no;
#pragma unroll
            for (int nt = 0; nt < 4; nt++) {
                ushort4 o;
                o.x = f2bf(acc[nt][mt][0]);
                o.y = f2bf(acc[nt][mt][1]);
                o.z = f2bf(acc[nt][mt][2]);
                o.w = f2bf(acc[nt][mt][3]);
                *(ushort4*)&D[base + nt * 16 + fq * 4] = o;
            }
        }
    }
}

// ---------------- combine: out[t] = w0*D[loc0] + w1*D[loc1] ----------------
__global__ __launch_bounds__(256) void combine(const unsigned short* __restrict__ D,
                                               const int* __restrict__ loc,
                                               const float* __restrict__ rw,
                                               float* __restrict__ out) {
    const int t = blockIdx.x;
    const int h = threadIdx.x * 8;
    const int l0 = loc[2 * t], l1 = loc[2 * t + 1];
    const float w0 = rw[2 * t], w1 = rw[2 * t + 1];
    float acc[8];
#pragma unroll
    for (int i = 0; i < 8; i++) acc[i] = 0.f;
    if (l0 >= 0) {
        ushort8v v = *(const ushort8v*)&D[(size_t)l0 * HDIM + h];
#pragma unroll
        for (int i = 0; i < 8; i++) acc[i] = w0 * bf2f(v[i]);
    }
    if (l1 >= 0) {
        ushort8v v = *(const ushort8v*)&D[(size_t)l1 * HDIM + h];
#pragma unroll
        for (int i = 0; i < 8; i++) acc[i] += w1 * bf2f(v[i]);
    }
    float4 o0 = make_float4(acc[0], acc[1], acc[2], acc[3]);
    float4 o1 = make_float4(acc[4], acc[5], acc[6], acc[7]);
    *(float4*)&out[(size_t)t * HDIM + h] = o0;
    *(float4*)&out[(size_t)t * HDIM + h + 4] = o1;
}

extern "C" void kernel_launch(void* const* d_in, const int* in_sizes, int n_in,
                              void* d_out, int out_size, void* d_ws, size_t ws_size,
                              hipStream_t stream) {
    const float* x  = (const float*)d_in[0];
    const float* gw = (const float*)d_in[1];
    const float* w1 = (const float*)d_in[2];
    const float* w2 = (const float*)d_in[3];
    const float* w3 = (const float*)d_in[4];
    float* out = (float*)d_out;

    char* ws = (char*)d_ws;
    size_t off = 0;
    int* sel = (int*)(ws + off);                off += (size_t)T_TOK * 2 * 4;   // 128K
    int* loc = (int*)(ws + off);                off += (size_t)T_TOK * 2 * 4;   // 128K
    float* rw = (float*)(ws + off);             off += (size_t)T_TOK * 2 * 4;   // 128K
    int* tok = (int*)(ws + off);                off += 82176;                    // 12*1707*4 padded
    int* counts = (int*)(ws + off);             off += 4096;                     // 12*64*4 padded
    unsigned short* w2b = (unsigned short*)(ws + off); off += (size_t)NEXP * HDIM * FDIM * 2;
    unsigned short* G   = (unsigned short*)(ws + off); off += (size_t)NEXP * CAP * FDIM * 2;
    // aliased region R (98.5 MB): phase 1 = part+w1b+w3b+xb; phase 2 = D (84 MB)
    char* R = ws + off;
    float* part = (float*)R;                                                    // 6,291,456 B
    unsigned short* w1b = (unsigned short*)(R + 6291456);                       // 12,582,912 B
    unsigned short* w3b = (unsigned short*)(R + 6291456 + 12582912);            // 12,582,912 B
    unsigned short* xb  = (unsigned short*)(R + 6291456 + 2 * 12582912);        // 67,108,864 B
    unsigned short* D   = (unsigned short*)R;                                   // 83,902,464 B

    const int nw4 = NEXP * FDIM * HDIM / 4;

    cvt3<<<2048, 256, 0, stream>>>((const float4*)w1, (ushort4*)w1b,
                                   (const float4*)w3, (ushort4*)w3b,
                                   (const float4*)w2, (ushort4*)w2b, nw4);
    gating_partial<<<dim3(T_TOK / 8, 2), 256, 0, stream>>>(x, gw, part, (ushort4*)xb);
    gating_top2<<<T_TOK / 256, 256, 0, stream>>>(part, sel, rw);
    route_count<<<64, 512, 0, stream>>>(sel, counts);
    route_emit<<<dim3(64, NEXP), 512, 0, stream>>>(sel, counts, tok, loc);
    up_gemm<<<dim3(14, 4, NEXP), 256, 0, stream>>>(xb, w1b, w3b, tok, G);
    down_gemm<<<dim3(14, 16, NEXP), 256, 0, stream>>>(G, w2b, D);
    combine<<<T_TOK, 256, 0, stream>>>(D, loc, rw, out);
}

// Round 4
// 441.356 us; speedup vs baseline: 1.4447x; 1.0584x over previous
//
#include <hip/hip_runtime.h>

#define T_TOK 16384
#define HDIM 2048
#define NEXP 12
#define FDIM 256
#define CAP 1707   // ceil(16384/12 * 1.25)

typedef __attribute__((ext_vector_type(8))) short short8;
typedef __attribute__((ext_vector_type(8))) unsigned short ushort8v;
typedef __attribute__((ext_vector_type(4))) float f32x4;

__device__ __forceinline__ unsigned short f2bf(float f) {
    unsigned int u = __float_as_uint(f);
    u += 0x7fffu + ((u >> 16) & 1u);   // RNE
    return (unsigned short)(u >> 16);
}
__device__ __forceinline__ float bf2f(unsigned short u) {
    return __uint_as_float(((unsigned int)u) << 16);
}

__device__ __forceinline__ void gload_lds16(const void* g, void* l) {
    __builtin_amdgcn_global_load_lds(
        (const __attribute__((address_space(1))) unsigned int*)g,
        (__attribute__((address_space(3))) unsigned int*)l, 16, 0, 0);
}

// full 64-lane sum, result valid in lane 63.
__device__ __forceinline__ float rsum64(float v) {
    v += __int_as_float(__builtin_amdgcn_update_dpp(0, __float_as_int(v), 0x118, 0xf, 0xf, true)); // shr 8
    v += __int_as_float(__builtin_amdgcn_update_dpp(0, __float_as_int(v), 0x114, 0xf, 0xf, true)); // shr 4
    v += __int_as_float(__builtin_amdgcn_update_dpp(0, __float_as_int(v), 0x112, 0xf, 0xf, true)); // shr 2
    v += __int_as_float(__builtin_amdgcn_update_dpp(0, __float_as_int(v), 0x111, 0xf, 0xf, true)); // shr 1
    v += __int_as_float(__builtin_amdgcn_update_dpp(0, __float_as_int(v), 0x142, 0xf, 0xf, true)); // bcast15
    v += __int_as_float(__builtin_amdgcn_update_dpp(0, __float_as_int(v), 0x143, 0xf, 0xf, true)); // bcast31
    return v;  // lane 63 holds the wave-wide sum
}

// ---------------- fp32 -> bf16 convert, all three weights in one launch ----------------
__global__ void cvt3(const float4* __restrict__ s0, ushort4* __restrict__ d0,
                     const float4* __restrict__ s1, ushort4* __restrict__ d1,
                     const float4* __restrict__ s2, ushort4* __restrict__ d2, int n4) {
    int i = blockIdx.x * blockDim.x + threadIdx.x;
    int stride = gridDim.x * blockDim.x;
    for (; i < 3 * n4; i += stride) {
        const float4* s; ushort4* d; int j;
        if (i < n4)            { s = s0; d = d0; j = i; }
        else if (i < 2 * n4)   { s = s1; d = d1; j = i - n4; }
        else                   { s = s2; d = d2; j = i - 2 * n4; }
        float4 v = s[j];
        ushort4 o;
        o.x = f2bf(v.x); o.y = f2bf(v.y); o.z = f2bf(v.z); o.w = f2bf(v.w);
        d[j] = o;
    }
}

// ---------------- gating: partial logits (fp32) + xb (bf16) ----------------
__global__ __launch_bounds__(256) void gating_partial(
    const float* __restrict__ x, const float* __restrict__ gw,
    float* __restrict__ part, ushort4* __restrict__ xb4) {
    const int tid = threadIdx.x;
    const int wid = tid >> 6, l = tid & 63;
    const int c = blockIdx.y * 4 + wid;          // chunk 0..7
    const int kbase = c * 256 + l * 4;
    const int t0 = blockIdx.x * 8;

    float4 g[12];
#pragma unroll
    for (int e = 0; e < 12; e++)
        g[e] = *(const float4*)(gw + e * HDIM + kbase);

    float4 xt[8];
#pragma unroll
    for (int u = 0; u < 8; u++)
        xt[u] = *(const float4*)(x + (size_t)(t0 + u) * HDIM + kbase);

#pragma unroll
    for (int u = 0; u < 8; u++) {
        ushort4 o;
        o.x = f2bf(xt[u].x); o.y = f2bf(xt[u].y);
        o.z = f2bf(xt[u].z); o.w = f2bf(xt[u].w);
        xb4[(size_t)(t0 + u) * (HDIM / 4) + c * 64 + l] = o;

        float a[12];
#pragma unroll
        for (int e = 0; e < 12; e++) {
            a[e] = g[e].x * xt[u].x;
            a[e] = fmaf(g[e].y, xt[u].y, a[e]);
            a[e] = fmaf(g[e].z, xt[u].z, a[e]);
            a[e] = fmaf(g[e].w, xt[u].w, a[e]);
        }
#pragma unroll
        for (int e = 0; e < 12; e++) a[e] = rsum64(a[e]);

        if (l == 63) {
            float* dst = part + ((size_t)c * T_TOK + t0 + u) * 12;
            *(float4*)(dst)     = make_float4(a[0], a[1], a[2], a[3]);
            *(float4*)(dst + 4) = make_float4(a[4], a[5], a[6], a[7]);
            *(float4*)(dst + 8) = make_float4(a[8], a[9], a[10], a[11]);
        }
    }
}

// ---------------- top-2 + renormalized weights ----------------
__global__ void gating_top2(const float* __restrict__ part,
                            int* __restrict__ sel, float* __restrict__ rw) {
    int t = blockIdx.x * 256 + threadIdx.x;
    float lg[12];
#pragma unroll
    for (int e = 0; e < 12; e++) lg[e] = 0.f;
    for (int c = 0; c < 8; c++) {
        const float* p = part + ((size_t)c * T_TOK + t) * 12;
#pragma unroll
        for (int e = 0; e < 12; e++) lg[e] += p[e];
    }
    float m1 = -1e30f, m2 = -1e30f; int i1 = 0, i2 = 0;
#pragma unroll
    for (int e = 0; e < 12; e++) {
        float v = lg[e];
        if (v > m1) { m2 = m1; i2 = i1; m1 = v; i1 = e; }
        else if (v > m2) { m2 = v; i2 = e; }
    }
    float r0 = 1.f / (1.f + expf(m2 - m1));
    sel[2 * t] = i1; sel[2 * t + 1] = i2;
    rw[2 * t] = r0;  rw[2 * t + 1] = 1.f - r0;
}

// ---------------- routing: per-chunk expert histogram ----------------
__global__ __launch_bounds__(512) void route_count(const int* __restrict__ sel,
                                                   int* __restrict__ counts) {
    __shared__ int h[NEXP];
    if (threadIdx.x < NEXP) h[threadIdx.x] = 0;
    __syncthreads();
    int f = blockIdx.x * 512 + threadIdx.x;
    int k = f >> 14, t = f & (T_TOK - 1);
    atomicAdd(&h[sel[2 * t + k]], 1);
    __syncthreads();
    if (threadIdx.x < NEXP) counts[threadIdx.x * 64 + blockIdx.x] = h[threadIdx.x];
}

// ---------------- routing: emit slot assignments (slot-major flat order) ----------------
__global__ __launch_bounds__(512) void route_emit(const int* __restrict__ sel,
                                                  const int* __restrict__ counts,
                                                  int* __restrict__ tok,
                                                  int* __restrict__ loc) {
    const int e = blockIdx.y, c = blockIdx.x;
    const int tid = threadIdx.x, lane = tid & 63, w = tid >> 6;
    __shared__ int wsum[8];
    int base = 0;
    for (int i = 0; i < c; i++) base += counts[e * 64 + i];
    int f = c * 512 + tid;
    int k = f >> 14, t = f & (T_TOK - 1);
    bool m = (sel[2 * t + k] == e);
    unsigned long long mask = __ballot(m);
    if (lane == 0) wsum[w] = __popcll(mask);
    __syncthreads();
    int off = 0, tot = 0;
#pragma unroll
    for (int i = 0; i < 8; i++) { int v = wsum[i]; tot += v; if (i < w) off += v; }
    if (m) {
        int pos = base + off + __popcll(mask & ((1ull << lane) - 1ull));
        if (pos < CAP) { tok[e * CAP + pos] = t; loc[2 * t + k] = e * CAP + pos; }
        else loc[2 * t + k] = -1;
    }
    if (c == 63) {  // pad unfilled slots with a valid token index (never combined)
        int total = base + tot;
        for (int p = total + tid; p < CAP; p += 512) tok[e * CAP + p] = 0;
    }
}

// ---------------- up-proj GEMM: G = silu((X@W1^T)*(X@W3^T)), bf16 out ----------------
// 1D grid, XCD-chunked: work = (bid%8)*84 + bid/8; work = ((e*14+m)*4 + cb)
// so the 4 cb-blocks sharing an A-tile run on the SAME XCD (L2 reuse).
// LDS XOR swizzle (both sides): global col slot and ds_read slot permuted by
// the involution slot ^= (row>>1)&3 -> rows spread over 8 bank-groups.
__global__ __launch_bounds__(256) void up_gemm(
    const unsigned short* __restrict__ xb,
    const unsigned short* __restrict__ w1b,
    const unsigned short* __restrict__ w3b,
    const int* __restrict__ tok,
    unsigned short* __restrict__ G) {
    __shared__ short As[128 * 32];
    __shared__ short B1s[64 * 32];
    __shared__ short B3s[64 * 32];
    const int bid = blockIdx.x;
    const int work = (bid & 7) * 84 + (bid >> 3);
    const int cb = (work & 3) * 64;
    const int rest = work >> 2;
    const int m0 = (rest % 14) * 128;
    const int e = rest / 14;
    const int tid = threadIdx.x, wid = tid >> 6, l = tid & 63;

    // swizzled global column slot (shorts): (l&3) ^ (row bits 1-2) where row = l>>2
    const int sl = ((l & 3) ^ ((l >> 3) & 3)) * 8;

    const int ar0 = wid * 32 + (l >> 2);
    const int ar1 = ar0 + 16;
    const int tk0 = tok[e * CAP + min(m0 + ar0, CAP - 1)];
    const int tk1 = tok[e * CAP + min(m0 + ar1, CAP - 1)];
    const unsigned short* ga0 = xb + (size_t)tk0 * HDIM + sl;
    const unsigned short* ga1 = xb + (size_t)tk1 * HDIM + sl;
    const int bn = wid * 16 + (l >> 2);
    const unsigned short* gb1 = w1b + ((size_t)(e * FDIM + cb + bn)) * HDIM + sl;
    const unsigned short* gb3 = w3b + ((size_t)(e * FDIM + cb + bn)) * HDIM + sl;
    short* lA0 = As + (wid * 32) * 32;
    short* lA1 = As + (wid * 32 + 16) * 32;
    short* lB1 = B1s + (wid * 16) * 32;
    short* lB3 = B3s + (wid * 16) * 32;

    const int wm = wid & 1, wn = wid >> 1;
    const int mo = wm * 64, no = wn * 32;
    const int fr = l & 15, fq = l >> 4;
    const int sx = (fq ^ ((fr >> 1) & 3)) * 8;   // swizzled read slot (shorts)

    const f32x4 zf = {0.f, 0.f, 0.f, 0.f};
    f32x4 acc1[2][4], acc3[2][4];   // [nt][mt], transposed product
#pragma unroll
    for (int nt = 0; nt < 2; nt++)
#pragma unroll
        for (int mt = 0; mt < 4; mt++) { acc1[nt][mt] = zf; acc3[nt][mt] = zf; }

    for (int kt = 0; kt < HDIM / 32; kt++) {
        gload_lds16(ga0 + kt * 32, lA0);
        gload_lds16(ga1 + kt * 32, lA1);
        gload_lds16(gb1 + kt * 32, lB1);
        gload_lds16(gb3 + kt * 32, lB3);
        __syncthreads();
        short8 a[4], b1[2], b3[2];
#pragma unroll
        for (int mt = 0; mt < 4; mt++)
            a[mt] = *(const short8*)&As[(mo + mt * 16 + fr) * 32 + sx];
#pragma unroll
        for (int nt = 0; nt < 2; nt++) {
            b1[nt] = *(const short8*)&B1s[(no + nt * 16 + fr) * 32 + sx];
            b3[nt] = *(const short8*)&B3s[(no + nt * 16 + fr) * 32 + sx];
        }
#pragma unroll
        for (int nt = 0; nt < 2; nt++)
#pragma unroll
            for (int mt = 0; mt < 4; mt++) {
                acc1[nt][mt] = __builtin_amdgcn_mfma_f32_16x16x32_bf16(b1[nt], a[mt], acc1[nt][mt], 0, 0, 0);
                acc3[nt][mt] = __builtin_amdgcn_mfma_f32_16x16x32_bf16(b3[nt], a[mt], acc3[nt][mt], 0, 0, 0);
            }
        __syncthreads();
    }
    // epilogue: thread holds rows r = mo+mt*16+fr (slot), cols cb+no+nt*16+fq*4+i
#pragma unroll
    for (int mt = 0; mt < 4; mt++) {
        int r = m0 + mo + mt * 16 + fr;
        if (r < CAP) {
            size_t base = ((size_t)e * CAP + r) * FDIM + cb + no;
#pragma unroll
            for (int nt = 0; nt < 2; nt++) {
                ushort4 o;
                float p;
                p = acc1[nt][mt][0] * acc3[nt][mt][0]; o.x = f2bf(p / (1.f + __expf(-p)));
                p = acc1[nt][mt][1] * acc3[nt][mt][1]; o.y = f2bf(p / (1.f + __expf(-p)));
                p = acc1[nt][mt][2] * acc3[nt][mt][2]; o.z = f2bf(p / (1.f + __expf(-p)));
                p = acc1[nt][mt][3] * acc3[nt][mt][3]; o.w = f2bf(p / (1.f + __expf(-p)));
                *(ushort4*)&G[base + nt * 16 + fq * 4] = o;
            }
        }
    }
}

// ---------------- down-proj GEMM: D[slot] = G[slot] @ W2^T, bf16, NO atomics ----------------
// 1D grid, XCD-chunked: work = (bid%8)*336 + bid/8; work = ((e*14+m)*16 + n)
__global__ __launch_bounds__(256) void down_gemm(
    const unsigned short* __restrict__ G,
    const unsigned short* __restrict__ w2b,
    unsigned short* __restrict__ D) {
    __shared__ short As[128 * 32];
    __shared__ short Bs[128 * 32];
    const int bid = blockIdx.x;
    const int work = (bid & 7) * 336 + (bid >> 3);
    const int n0 = (work & 15) * 128;
    const int rest = work >> 4;
    const int m0 = (rest % 14) * 128;
    const int e = rest / 14;
    const int tid = threadIdx.x, wid = tid >> 6, l = tid & 63;

    const int sl = ((l & 3) ^ ((l >> 3) & 3)) * 8;

    const int r0 = wid * 32 + (l >> 2);
    const int r1 = r0 + 16;
    const unsigned short* ga0 = G + ((size_t)e * CAP + min(m0 + r0, CAP - 1)) * FDIM + sl;
    const unsigned short* ga1 = G + ((size_t)e * CAP + min(m0 + r1, CAP - 1)) * FDIM + sl;
    const unsigned short* gb0 = w2b + ((size_t)(e * HDIM + n0 + r0)) * FDIM + sl;
    const unsigned short* gb1 = w2b + ((size_t)(e * HDIM + n0 + r1)) * FDIM + sl;
    short* lA0 = As + (wid * 32) * 32;
    short* lA1 = As + (wid * 32 + 16) * 32;
    short* lB0 = Bs + (wid * 32) * 32;
    short* lB1 = Bs + (wid * 32 + 16) * 32;

    const int wm = wid & 1, wn = wid >> 1;
    const int mo = wm * 64, no = wn * 64;
    const int fr = l & 15, fq = l >> 4;
    const int sx = (fq ^ ((fr >> 1) & 3)) * 8;

    const f32x4 zf = {0.f, 0.f, 0.f, 0.f};
    f32x4 acc[4][4];   // [nt][mt], transposed product
#pragma unroll
    for (int nt = 0; nt < 4; nt++)
#pragma unroll
        for (int mt = 0; mt < 4; mt++) acc[nt][mt] = zf;

    for (int kt = 0; kt < FDIM / 32; kt++) {
        gload_lds16(ga0 + kt * 32, lA0);
        gload_lds16(ga1 + kt * 32, lA1);
        gload_lds16(gb0 + kt * 32, lB0);
        gload_lds16(gb1 + kt * 32, lB1);
        __syncthreads();
        short8 a[4], b[4];
#pragma unroll
        for (int mt = 0; mt < 4; mt++)
            a[mt] = *(const short8*)&As[(mo + mt * 16 + fr) * 32 + sx];
#pragma unroll
        for (int nt = 0; nt < 4; nt++)
            b[nt] = *(const short8*)&Bs[(no + nt * 16 + fr) * 32 + sx];
#pragma unroll
        for (int nt = 0; nt < 4; nt++)
#pragma unroll
            for (int mt = 0; mt < 4; mt++)
                acc[nt][mt] = __builtin_amdgcn_mfma_f32_16x16x32_bf16(b[nt], a[mt], acc[nt][mt], 0, 0, 0);
        __syncthreads();
    }
    // thread holds rows r = mo+mt*16+fr (slot), cols n0+no+nt*16+fq*4+i (H)
#pragma unroll
    for (int mt = 0; mt < 4; mt++) {
        int r = m0 + mo + mt * 16 + fr;
        if (r < CAP) {
            size_t base = ((size_t)e * CAP + r) * HDIM + n0 + no;
#pragma unroll
            for (int nt = 0; nt < 4; nt++) {
                ushort4 o;
                o.x = f2bf(acc[nt][mt][0]);
                o.y = f2bf(acc[nt][mt][1]);
                o.z = f2bf(acc[nt][mt][2]);
                o.w = f2bf(acc[nt][mt][3]);
                *(ushort4*)&D[base + nt * 16 + fq * 4] = o;
            }
        }
    }
}

// ---------------- combine: out[t] = w0*D[loc0] + w1*D[loc1] ----------------
__global__ __launch_bounds__(256) void combine(const unsigned short* __restrict__ D,
                                               const int* __restrict__ loc,
                                               const float* __restrict__ rw,
                                               float* __restrict__ out) {
    const int t = blockIdx.x;
    const int h = threadIdx.x * 8;
    const int l0 = loc[2 * t], l1 = loc[2 * t + 1];
    const float w0 = rw[2 * t], w1 = rw[2 * t + 1];
    float acc[8];
#pragma unroll
    for (int i = 0; i < 8; i++) acc[i] = 0.f;
    if (l0 >= 0) {
        ushort8v v = *(const ushort8v*)&D[(size_t)l0 * HDIM + h];
#pragma unroll
        for (int i = 0; i < 8; i++) acc[i] = w0 * bf2f(v[i]);
    }
    if (l1 >= 0) {
        ushort8v v = *(const ushort8v*)&D[(size_t)l1 * HDIM + h];
#pragma unroll
        for (int i = 0; i < 8; i++) acc[i] += w1 * bf2f(v[i]);
    }
    float4 o0 = make_float4(acc[0], acc[1], acc[2], acc[3]);
    float4 o1 = make_float4(acc[4], acc[5], acc[6], acc[7]);
    *(float4*)&out[(size_t)t * HDIM + h] = o0;
    *(float4*)&out[(size_t)t * HDIM + h + 4] = o1;
}

extern "C" void kernel_launch(void* const* d_in, const int* in_sizes, int n_in,
                              void* d_out, int out_size, void* d_ws, size_t ws_size,
                              hipStream_t stream) {
    const float* x  = (const float*)d_in[0];
    const float* gw = (const float*)d_in[1];
    const float* w1 = (const float*)d_in[2];
    const float* w2 = (const float*)d_in[3];
    const float* w3 = (const float*)d_in[4];
    float* out = (float*)d_out;

    char* ws = (char*)d_ws;
    size_t off = 0;
    int* sel = (int*)(ws + off);                off += (size_t)T_TOK * 2 * 4;   // 128K
    int* loc = (int*)(ws + off);                off += (size_t)T_TOK * 2 * 4;   // 128K
    float* rw = (float*)(ws + off);             off += (size_t)T_TOK * 2 * 4;   // 128K
    int* tok = (int*)(ws + off);                off += 82176;                    // 12*1707*4 padded
    int* counts = (int*)(ws + off);             off += 4096;                     // 12*64*4 padded
    unsigned short* w2b = (unsigned short*)(ws + off); off += (size_t)NEXP * HDIM * FDIM * 2;
    unsigned short* G   = (unsigned short*)(ws + off); off += (size_t)NEXP * CAP * FDIM * 2;
    // aliased region R (98.5 MB): phase 1 = part+w1b+w3b+xb; phase 2 = D (84 MB)
    char* R = ws + off;
    float* part = (float*)R;                                                    // 6,291,456 B
    unsigned short* w1b = (unsigned short*)(R + 6291456);                       // 12,582,912 B
    unsigned short* w3b = (unsigned short*)(R + 6291456 + 12582912);            // 12,582,912 B
    unsigned short* xb  = (unsigned short*)(R + 6291456 + 2 * 12582912);        // 67,108,864 B
    unsigned short* D   = (unsigned short*)R;                                   // 83,902,464 B

    const int nw4 = NEXP * FDIM * HDIM / 4;

    cvt3<<<2048, 256, 0, stream>>>((const float4*)w1, (ushort4*)w1b,
                                   (const float4*)w3, (ushort4*)w3b,
                                   (const float4*)w2, (ushort4*)w2b, nw4);
    gating_partial<<<dim3(T_TOK / 8, 2), 256, 0, stream>>>(x, gw, part, (ushort4*)xb);
    gating_top2<<<T_TOK / 256, 256, 0, stream>>>(part, sel, rw);
    route_count<<<64, 512, 0, stream>>>(sel, counts);
    route_emit<<<dim3(64, NEXP), 512, 0, stream>>>(sel, counts, tok, loc);
    up_gemm<<<672, 256, 0, stream>>>(xb, w1b, w3b, tok, G);
    down_gemm<<<2688, 256, 0, stream>>>(G, w2b, D);
    combine<<<T_TOK, 256, 0, stream>>>(D, loc, rw, out);
}